// Round 16
// baseline (268.478 us; speedup 1.0000x reference)
//
#include <hip/hip_runtime.h>

// PolyConv: h = sum_k theta[k] * L_sym^k x,  L_sym = I - D^{-1/2} A D^{-1/2}
// N=100000 nodes, E=1600000 edges, F=64 features, 5 theta terms.
//
// Round 16: k_gather pipeline deepened to 3 stages (rows for iter i and i+1
// resident, csr for i+2 in flight, csr for i+3 fetched per iteration) --
// doubles row bytes in flight per wave vs r14's depth-2, no granularity
// change. Epilogue self-row (+ LAST's xb/g1/g2) prefetched before the
// 16-shfl butterfly to hide its latency.

constexpr int kF = 64;
constexpr int BSHIFT = 8;             // bucket = dst >> 8  (256 nodes/bucket)
constexpr int NB = 1 << BSHIFT;       // 256 nodes per bucket
constexpr int TILE = 2048;            // edges per phase-A block (4/thread)
constexpr int KMAX = 512;             // array bound for K (=391)

static __device__ __forceinline__ float bfl(unsigned u) {        // low bf16 -> f32
    return __uint_as_float(u << 16);
}
static __device__ __forceinline__ float bfh(unsigned u) {        // high bf16 -> f32
    return __uint_as_float(u & 0xffff0000u);
}
static __device__ __forceinline__ unsigned f2bf(float f) {       // RNE f32 -> bf16
    unsigned u = __float_as_uint(f);
    return (u + 0x7fffu + ((u >> 16) & 1u)) >> 16;
}
static __device__ __forceinline__ unsigned pack2(float a, float b) {
    return f2bf(a) | (f2bf(b) << 16);
}

// Phase A: multisplit edges into K buckets (hist -> reserve -> direct global
// scatter with LDS cursors). dst/src register-cached across phases.
// Fused x (fp32) -> xb (bf16) conversion.
__global__ void k_binA(const int* __restrict__ src, const int* __restrict__ dst,
                       unsigned* __restrict__ pairs, int* __restrict__ gcursor,
                       const float4* __restrict__ x4, uint4* __restrict__ xb4,
                       int n8, int E, int K, int cap) {
    __shared__ int hist[KMAX];
    __shared__ int gb[KMAX];
    const int tid = threadIdx.x;        // blockDim = 512
    const long long tb = (long long)blockIdx.x * TILE;
    const int tcount = (int)min((long long)TILE, (long long)E - tb);

    // fused x -> bf16 convert (disjoint slice per block)
    {
        int per = (n8 + gridDim.x - 1) / (int)gridDim.x;
        int b0 = blockIdx.x * per;
        int b1 = min(b0 + per, n8);
        for (int i = b0 + tid; i < b1; i += 512) {
            float4 a = x4[2 * i];
            float4 b = x4[2 * i + 1];
            uint4 o;
            o.x = pack2(a.x, a.y);
            o.y = pack2(a.z, a.w);
            o.z = pack2(b.x, b.y);
            o.w = pack2(b.z, b.w);
            xb4[i] = o;
        }
    }

    hist[tid] = 0;
    __syncthreads();
    int dc[4], sc[4];
    #pragma unroll
    for (int k = 0; k < 4; ++k) {
        int i = tid + k * 512;
        if (i < tcount) {
            dc[k] = dst[tb + i];
            sc[k] = src[tb + i];
            atomicAdd(&hist[dc[k] >> BSHIFT], 1);
        } else {
            dc[k] = -1;
        }
    }
    __syncthreads();
    int hv = hist[tid];
    gb[tid] = (tid < K && hv > 0) ? atomicAdd(&gcursor[tid], hv) : 0;
    hist[tid] = 0;                       // reuse as local cursor
    __syncthreads();
    #pragma unroll
    for (int k = 0; k < 4; ++k) {
        if (dc[k] >= 0) {
            int d = dc[k];
            int b = d >> BSHIFT;
            int pos = atomicAdd(&hist[b], 1);
            pairs[(size_t)b * cap + gb[b] + pos] =
                ((unsigned)(d & (NB - 1)) << 23) | (unsigned)sc[k];
        }
    }
}

// Phase B: one block (512 thr) per bucket of 256 nodes. In-kernel gbase
// scan, per-node counts -> LDS scan -> rp/dinv2/rdeg, scatter plain src ints
// to csr via absolute LDS cursors, then convert own bucket's xb->g0 slice
// with LDS dinv (fused former k_g0).
__global__ void k_binB(const unsigned* __restrict__ pairs, const int* __restrict__ gcursor,
                       int* __restrict__ rp, float* __restrict__ dinv2,
                       float* __restrict__ rdeg, int* __restrict__ csr,
                       const uint4* __restrict__ xb, uint4* __restrict__ g0,
                       int N, int E, int K, int cap) {
    __shared__ int gsc[KMAX];
    __shared__ int cnt[NB];
    __shared__ int stmp[NB];
    __shared__ int cur[NB];
    __shared__ float sdinv[NB];
    const int b = blockIdx.x;
    const int tid = threadIdx.x;        // blockDim = 512

    int gv = (tid < K) ? gcursor[tid] : 0;
    gsc[tid] = gv;
    __syncthreads();
    for (int o = 1; o < KMAX; o <<= 1) {
        int t = (tid >= o) ? gsc[tid - o] : 0;
        __syncthreads();
        gsc[tid] += t;
        __syncthreads();
    }
    const int ecnt = gcursor[b];
    const int base = gsc[b] - ecnt;     // inclusive - own = exclusive
    const unsigned* bp = pairs + (size_t)b * cap;

    if (tid < NB) cnt[tid] = 0;
    __syncthreads();
    for (int i = tid; i < ecnt; i += 512)
        atomicAdd(&cnt[bp[i] >> 23], 1);
    __syncthreads();
    int v = (tid < NB) ? cnt[tid] : 0;
    if (tid < NB) stmp[tid] = v;
    __syncthreads();
    for (int o = 1; o < NB; o <<= 1) {
        int t = (tid >= o && tid < NB) ? stmp[tid - o] : 0;
        __syncthreads();
        if (tid < NB) stmp[tid] += t;
        __syncthreads();
    }
    int node = (b << BSHIFT) + tid;
    if (tid < NB) {
        int abs0 = base + stmp[tid] - v;            // exclusive, absolute
        cur[tid] = abs0;
        float d = fmaxf((float)v, 1.0f);
        sdinv[tid] = rsqrtf(d);
        if (node < N) {
            rp[node] = abs0;
            dinv2[node] = 1.0f / d;
            rdeg[node]  = sqrtf(d);
        }
    }
    if (b == K - 1 && tid == 0) rp[N] = E;
    __syncthreads();
    for (int i = tid; i < ecnt; i += 512) {
        unsigned p = bp[i];
        int pos = atomicAdd(&cur[p >> 23], 1);      // absolute csr index
        csr[pos] = (int)(p & 0x7FFFFFu);
    }
    // fused g0 = bf16(dinv * x) for this bucket's nodes (streaming 32KB)
    const int nbase = b << BSHIFT;
    const int qmax = min(NB, N - nbase) << 3;       // 8 uint4 per node
    const uint4* xbp = xb + ((size_t)nbase << 3);
    uint4* g0p = g0 + ((size_t)nbase << 3);
    for (int q = tid; q < qmax; q += 512) {
        float di = sdinv[q >> 3];
        uint4 xv = xbp[q];
        uint4 o;
        o.x = pack2(di * bfl(xv.x), di * bfh(xv.x));
        o.y = pack2(di * bfl(xv.y), di * bfh(xv.y));
        o.z = pack2(di * bfl(xv.z), di * bfh(xv.z));
        o.w = pack2(di * bfl(xv.w), di * bfh(xv.w));
        g0p[q] = o;
    }
}

// TWO nodes per wave, bf16 scaled-feature tables (128B rows), depth-3
// software pipeline: rows for iter i and i+1 resident, csr for i+2 in
// flight, csr for i+3 fetched per iteration. Lane l: half = l>>5,
// r = (l>>3)&3, c = l&7. Butterfly ^8,^16 -> lanes {0..7,32..39}.
// Epilogue self-row (+ LAST operands) prefetched before the butterfly.
// !LAST: gout[d] = bf16(gin[d] - dinv2[d]*acc)
//  LAST: h[d] = t0*xb[d] + rdeg[d]*(t1*g1+t2*g2+t3*gin+t4*g4),
//        g4 = gin[d] - dinv2[d]*acc in-register.
template <bool LAST>
__global__ void k_gather(const int* __restrict__ rp, const int* __restrict__ csr,
                         const unsigned short* __restrict__ gin,
                         const float* __restrict__ dinv2,
                         unsigned short* __restrict__ gout,
                         const unsigned short* __restrict__ xb,
                         const unsigned short* __restrict__ g1t,
                         const unsigned short* __restrict__ g2t,
                         const float* __restrict__ rdeg,
                         float* __restrict__ h, int n,
                         float t0, float t1, float t2, float t3, float t4) {
    int wid = (blockIdx.x * blockDim.x + threadIdx.x) >> 6;
    int lane = threadIdx.x & 63;
    int half = lane >> 5;
    int r = (lane >> 3) & 3;
    int c = lane & 7;
    int node = wid * 2 + half;
    if (wid * 2 >= n) return;
    bool valid = node < n;
    int beg = valid ? rp[node] : 0;
    int end = valid ? rp[node + 1] : 0;
    int len = end - beg;
    int olen = __shfl_xor(len, 32, 64);
    int mlen = (len > olen) ? len : olen;   // pair max -> uniform trip count

    float acc[8] = {0.f, 0.f, 0.f, 0.f, 0.f, 0.f, 0.f, 0.f};

    // depth-3 pipeline state
    uint4 r0a = make_uint4(0,0,0,0), r0b = make_uint4(0,0,0,0);  // iter i rows
    uint4 r1a = make_uint4(0,0,0,0), r1b = make_uint4(0,0,0,0);  // iter i+1 rows
    float w0a = 0.f, w0b = 0.f, w1a = 0.f, w1b = 0.f;
    int   s2a = 0, s2b = 0;                                      // iter i+2 csr
    float w2a = 0.f, w2b = 0.f;
    if (mlen > 0) {
        int j1 = beg + r, j2 = j1 + 4;
        bool o1 = j1 < end, o2 = j2 < end;
        int sa = csr[o1 ? j1 : 0];
        int sb = csr[o2 ? j2 : 0];
        w0a = o1 ? 1.f : 0.f;
        w0b = o2 ? 1.f : 0.f;
        r0a = *(const uint4*)(gin + ((size_t)sa << 6) + (c << 3));
        r0b = *(const uint4*)(gin + ((size_t)sb << 6) + (c << 3));
        int j1b = beg + 8 + r, j2b = j1b + 4;
        bool vb = 8 < mlen;
        bool b1 = vb && (j1b < end), b2 = vb && (j2b < end);
        int sc1 = csr[b1 ? j1b : 0];
        int sc2 = csr[b2 ? j2b : 0];
        w1a = b1 ? 1.f : 0.f;
        w1b = b2 ? 1.f : 0.f;
        r1a = *(const uint4*)(gin + ((size_t)sc1 << 6) + (c << 3));
        r1b = *(const uint4*)(gin + ((size_t)sc2 << 6) + (c << 3));
        int j1c = beg + 16 + r, j2c = j1c + 4;
        bool vc = 16 < mlen;
        bool c1 = vc && (j1c < end), c2 = vc && (j2c < end);
        s2a = csr[c1 ? j1c : 0];
        s2b = csr[c2 ? j2c : 0];
        w2a = c1 ? 1.f : 0.f;
        w2b = c2 ? 1.f : 0.f;
    }
    for (int i = 0; i < mlen; i += 8) {
        // issue iter i+2 rows (from prefetched csr indices)
        uint4 r2a = *(const uint4*)(gin + ((size_t)s2a << 6) + (c << 3));
        uint4 r2b = *(const uint4*)(gin + ((size_t)s2b << 6) + (c << 3));
        // fetch csr for iter i+3
        int j1n = beg + i + 24 + r, j2n = j1n + 4;
        bool vn = (i + 24) < mlen;
        bool t1c = vn && (j1n < end), t2c = vn && (j2n < end);
        int s3a = csr[t1c ? j1n : 0];
        int s3b = csr[t2c ? j2n : 0];
        float w3a = t1c ? 1.f : 0.f, w3b = t2c ? 1.f : 0.f;
        // accumulate iter i rows
        acc[0] += w0a * bfl(r0a.x); acc[1] += w0a * bfh(r0a.x);
        acc[2] += w0a * bfl(r0a.y); acc[3] += w0a * bfh(r0a.y);
        acc[4] += w0a * bfl(r0a.z); acc[5] += w0a * bfh(r0a.z);
        acc[6] += w0a * bfl(r0a.w); acc[7] += w0a * bfh(r0a.w);
        acc[0] += w0b * bfl(r0b.x); acc[1] += w0b * bfh(r0b.x);
        acc[2] += w0b * bfl(r0b.y); acc[3] += w0b * bfh(r0b.y);
        acc[4] += w0b * bfl(r0b.z); acc[5] += w0b * bfh(r0b.z);
        acc[6] += w0b * bfl(r0b.w); acc[7] += w0b * bfh(r0b.w);
        // rotate pipeline
        r0a = r1a; r0b = r1b; w0a = w1a; w0b = w1b;
        r1a = r2a; r1b = r2b; w1a = w2a; w1b = w2b;
        s2a = s3a; s2b = s3b; w2a = w3a; w2b = w3b;
    }

    // prefetch epilogue operands before the butterfly hides their latency
    size_t off = ((size_t)node << 6) + (c << 3);
    uint4 rr = make_uint4(0,0,0,0), xv = make_uint4(0,0,0,0);
    uint4 ga = make_uint4(0,0,0,0), gb2 = make_uint4(0,0,0,0);
    float d2 = 0.f, rd = 0.f;
    if (r == 0 && valid) {
        rr = *(const uint4*)(gin + off);
        d2 = dinv2[node];
        if (LAST) {
            xv  = *(const uint4*)(xb + off);
            ga  = *(const uint4*)(g1t + off);
            gb2 = *(const uint4*)(g2t + off);
            rd  = rdeg[node];
        }
    }

    #pragma unroll
    for (int m = 8; m <= 16; m <<= 1) {
        #pragma unroll
        for (int i = 0; i < 8; ++i)
            acc[i] += __shfl_xor(acc[i], m, 64);
    }

    if (r == 0 && valid) {                   // lanes 0..7 and 32..39
        float v[8];
        v[0] = bfl(rr.x) - d2 * acc[0]; v[1] = bfh(rr.x) - d2 * acc[1];
        v[2] = bfl(rr.y) - d2 * acc[2]; v[3] = bfh(rr.y) - d2 * acc[3];
        v[4] = bfl(rr.z) - d2 * acc[4]; v[5] = bfh(rr.z) - d2 * acc[5];
        v[6] = bfl(rr.w) - d2 * acc[6]; v[7] = bfh(rr.w) - d2 * acc[7];
        if (!LAST) {
            uint4 o;
            o.x = pack2(v[0], v[1]);
            o.y = pack2(v[2], v[3]);
            o.z = pack2(v[4], v[5]);
            o.w = pack2(v[6], v[7]);
            *(uint4*)(gout + off) = o;
        } else {
            float s1 = rd * t1, s2 = rd * t2, s3 = rd * t3, s4 = rd * t4;
            float4 h0, h1;
            h0.x = t0 * bfl(xv.x) + s1 * bfl(ga.x) + s2 * bfl(gb2.x) + s3 * bfl(rr.x) + s4 * v[0];
            h0.y = t0 * bfh(xv.x) + s1 * bfh(ga.x) + s2 * bfh(gb2.x) + s3 * bfh(rr.x) + s4 * v[1];
            h0.z = t0 * bfl(xv.y) + s1 * bfl(ga.y) + s2 * bfl(gb2.y) + s3 * bfl(rr.y) + s4 * v[2];
            h0.w = t0 * bfh(xv.y) + s1 * bfh(ga.y) + s2 * bfh(gb2.y) + s3 * bfh(rr.y) + s4 * v[3];
            h1.x = t0 * bfl(xv.z) + s1 * bfl(ga.z) + s2 * bfl(gb2.z) + s3 * bfl(rr.z) + s4 * v[4];
            h1.y = t0 * bfh(xv.z) + s1 * bfh(ga.z) + s2 * bfh(gb2.z) + s3 * bfh(rr.z) + s4 * v[5];
            h1.z = t0 * bfl(xv.w) + s1 * bfl(ga.w) + s2 * bfl(gb2.w) + s3 * bfl(rr.w) + s4 * v[6];
            h1.w = t0 * bfh(xv.w) + s1 * bfh(ga.w) + s2 * bfh(gb2.w) + s3 * bfh(rr.w) + s4 * v[7];
            *(float4*)(h + off) = h0;
            *(float4*)(h + off + 4) = h1;
        }
    }
}

extern "C" void kernel_launch(void* const* d_in, const int* in_sizes, int n_in,
                              void* d_out, int out_size, void* d_ws, size_t ws_size,
                              hipStream_t stream) {
    const float* x  = (const float*)d_in[0];
    const int*   ei = (const int*)d_in[1];   // edge_index [2, E] row-major
    const int N = in_sizes[0] / kF;
    const int E = in_sizes[1] / 2;
    const int* src = ei;
    const int* dst = ei + E;
    float* h = (float*)d_out;

    const int K = (N + NB - 1) >> BSHIFT;         // 391 buckets (K <= KMAX)
    const int cap = 2 * ((E + K - 1) / K);        // per-bucket capacity

    // workspace (~73 MB): gcursor | rp | dinv2 | rdeg | csr | xb | g0..g3 |
    // pairs (aliases g3: g3 first written in pass 3, pairs dead after binB)
    char* ws = (char*)d_ws;
    size_t off = 0;
    auto carve = [&](size_t bytes) {
        void* p = ws + off;
        off = (off + bytes + 511) & ~(size_t)511;
        return p;
    };
    int*            gcursor = (int*)carve((size_t)K * 4);
    int*            rp      = (int*)carve((size_t)(N + 1) * 4);
    float*          dinv2   = (float*)carve((size_t)N * 4);
    float*          rdeg    = (float*)carve((size_t)N * 4);
    int*            csr     = (int*)carve((size_t)E * 4);
    unsigned short* xb      = (unsigned short*)carve((size_t)N * kF * 2);
    unsigned short* g0      = (unsigned short*)carve((size_t)N * kF * 2);
    unsigned short* g1      = (unsigned short*)carve((size_t)N * kF * 2);
    unsigned short* g2      = (unsigned short*)carve((size_t)N * kF * 2);
    size_t gbytes = (size_t)N * kF * 2;
    size_t pbytes = (size_t)K * cap * 4;
    unsigned short* g3      = (unsigned short*)carve(gbytes > pbytes ? gbytes : pbytes);
    unsigned*       pairs   = (unsigned*)g3;       // alias (see above)

    const float theta[5] = {0.6f, -0.4f, 0.3f, -0.2f, 0.1f};
    const int n8 = N * kF / 8;

    // ---- CSR build (multisplit) with fused x->bf16 convert and g0 ----
    hipMemsetAsync(gcursor, 0, (size_t)K * 4, stream);
    k_binA<<<(E + TILE - 1) / TILE, 512, 0, stream>>>(src, dst, pairs, gcursor,
                                                      (const float4*)x, (uint4*)xb,
                                                      n8, E, K, cap);
    k_binB<<<K, 512, 0, stream>>>(pairs, gcursor, rp, dinv2, rdeg, csr,
                                  (const uint4*)xb, (uint4*)g0, N, E, K, cap);

    // ---- 4 gather passes; pass 4 fuses the h-combine epilogue ----
    const int nwaves = (N + 1) / 2;                // 2 nodes per wave
    const int gblocks = (nwaves + 3) / 4;          // 4 waves per 256-thread block
    k_gather<false><<<gblocks, 256, 0, stream>>>(rp, csr, g0, dinv2, g1,
                                                 nullptr, nullptr, nullptr, nullptr,
                                                 nullptr, N, 0, 0, 0, 0, 0);
    k_gather<false><<<gblocks, 256, 0, stream>>>(rp, csr, g1, dinv2, g2,
                                                 nullptr, nullptr, nullptr, nullptr,
                                                 nullptr, N, 0, 0, 0, 0, 0);
    k_gather<false><<<gblocks, 256, 0, stream>>>(rp, csr, g2, dinv2, g3,
                                                 nullptr, nullptr, nullptr, nullptr,
                                                 nullptr, N, 0, 0, 0, 0, 0);
    k_gather<true><<<gblocks, 256, 0, stream>>>(rp, csr, g3, dinv2, nullptr,
                                                xb, g1, g2, rdeg, h, N,
                                                theta[0], theta[1], theta[2],
                                                theta[3], theta[4]);
}